// Round 2
// baseline (680.496 us; speedup 1.0000x reference)
//
#include <hip/hip_runtime.h>

// Problem constants (fixed by the reference module).
#define ROWS 8192
#define COLS 8192

// float4 with 4-byte alignment so the compiler may emit global_load_dwordx4
// at dword (not 16B) alignment — slice runs start at arbitrary columns.
typedef float floatx4 __attribute__((ext_vector_type(4)));
typedef floatx4 __attribute__((aligned(4))) floatx4u;

// --------------------------------------------------------------------------
// Kernel 1: build flat column-gather index. One block, 1024 threads.
// Phase 1: block-wide scan of slice lengths -> offset table in LDS.
// Phase 2: all threads cooperatively fill col_idx with coalesced stores,
//          mapping j -> slice via LDS binary search.
// --------------------------------------------------------------------------
__global__ void build_idx_kernel(const int* __restrict__ slices, int n_slices,
                                 int* __restrict__ col_idx, int cols_out) {
    __shared__ int sh[1024];     // scan workspace (inclusive prefix of lengths)
    __shared__ int offs[1024];   // exclusive prefix (slice start offset in out)
    __shared__ int starts[1024]; // slice start column
    const int t = threadIdx.x;

    int s = 0, L = 0;
    if (t < n_slices) {
        s = slices[2 * t];
        L = slices[2 * t + 1] - s;
    }
    starts[t] = s;
    sh[t] = L;
    __syncthreads();
    #pragma unroll
    for (int d = 1; d < 1024; d <<= 1) {
        int v = (t >= d) ? sh[t - d] : 0;
        __syncthreads();
        sh[t] += v;
        __syncthreads();
    }
    offs[t] = sh[t] - L;  // exclusive prefix
    __syncthreads();

    // Cooperative fill: coalesced stores, LDS binary search for the slice.
    for (int j = t; j < cols_out; j += 1024) {
        int lo = 0, hi = n_slices - 1;
        while (lo < hi) {                       // find max i with offs[i] <= j
            int mid = (lo + hi + 1) >> 1;
            if (offs[mid] <= j) lo = mid; else hi = mid - 1;
        }
        col_idx[j] = starts[lo] + (j - offs[lo]);
    }
}

// --------------------------------------------------------------------------
// Kernel 2: gather, one output ROW per block.
// Reads concentrate in one 32KB input row; writes are one contiguous 50KB
// stream -> 2 DRAM streams per block (was 16). float4 stores always
// (cols_out % 4 == 0, row stride 16B-aligned); float4 loads when the quad's
// columns form a contiguous run (~85% of quads), else 4 scalar loads.
// --------------------------------------------------------------------------
__global__ void gather_kernel(const float* __restrict__ in,
                              const int* __restrict__ col_idx,
                              float* __restrict__ out, int cols_out) {
    const int row = blockIdx.x;
    const float* __restrict__ inr = in + (size_t)row * COLS;
    float* __restrict__ outr = out + (size_t)row * cols_out;
    const int nquads = cols_out >> 2;

    for (int q = threadIdx.x; q < nquads; q += blockDim.x) {
        const int4 c = ((const int4*)col_idx)[q];
        floatx4 v;
        if (c.y == c.x + 1 && c.z == c.x + 2 && c.w == c.x + 3) {
            v = *(const floatx4u*)(inr + c.x);      // contiguous run
        } else {
            v.x = inr[c.x]; v.y = inr[c.y]; v.z = inr[c.z]; v.w = inr[c.w];
        }
        *(floatx4*)(outr + 4 * q) = v;              // 16B-aligned store
    }
    // Tail (cols_out % 4 != 0) — not hit for 12500 but kept for generality.
    const int tail0 = nquads << 2;
    for (int j = tail0 + threadIdx.x; j < cols_out; j += blockDim.x)
        outr[j] = inr[col_idx[j]];
}

extern "C" void kernel_launch(void* const* d_in, const int* in_sizes, int n_in,
                              void* d_out, int out_size, void* d_ws, size_t ws_size,
                              hipStream_t stream) {
    const float* in = (const float*)d_in[0];
    const int* slices = (const int*)d_in[1];
    float* out = (float*)d_out;

    const int n_slices = in_sizes[1] / 2;   // [n_slices, 2] flat
    const int cols_out = out_size / ROWS;   // 12500

    int* col_idx = (int*)d_ws;              // 50 KB scratch

    build_idx_kernel<<<1, 1024, 0, stream>>>(slices, n_slices, col_idx, cols_out);
    gather_kernel<<<ROWS, 256, 0, stream>>>(in, col_idx, out, cols_out);
}